// Round 1
// baseline (1052.662 us; speedup 1.0000x reference)
//
#include <hip/hip_runtime.h>

// ELKUNet forward on MI355X.
// Layout decisions:
//  - 1 wave (64 lanes) = 1 point; lane = channel (C=64).
//  - Dense voxel grid (256^3 int32 = 67MB) in workspace for neighbor lookup.
//  - Segment sums via global f32 atomics (avg 6.1 pts/seg -> low contention).
//  - Device-side dtype probe: harness may hand us bf16-cast or f32 tensors;
//    we detect which by exponent statistics and branch uniformly.

#define EPSV 1e-6f

__device__ __forceinline__ float wave_sum(float v) {
#pragma unroll
    for (int off = 32; off >= 1; off >>= 1)
        v += __shfl_xor(v, off, 64);
    return v;
}

// load element idx of a "float-ish" tensor: f32m ? f32 : bf16 (high-16-bits)
__device__ __forceinline__ float ldf(const void* p, size_t idx, int f32m) {
    if (f32m) return ((const float*)p)[idx];
    unsigned int w = ((unsigned int)((const unsigned short*)p)[idx]) << 16;
    return __uint_as_float(w);
}

// ---- dtype detection: if data is f32 read as u16, even indices are mantissa
// low-halves -> uniform random "exponent" bits; true bf16 gaussians stay in
// a narrow exponent band. One wave scans 2048 even-index entries.
__global__ void k_detect(const unsigned short* __restrict__ u, int* __restrict__ flag) {
    int wild = 0;
    for (int k = threadIdx.x; k < 2048; k += 64) {
        int e = (u[2 * k] >> 7) & 0xFF;
        if (e > 140 || (e < 100 && e != 0)) wild++;
    }
#pragma unroll
    for (int off = 32; off >= 1; off >>= 1) wild += __shfl_xor(wild, off, 64);
    if (threadIdx.x == 0) *flag = (wild > 200) ? 1 : 0;  // 1 => f32 mode
}

__global__ void k_scatter(const int* __restrict__ coords, int* __restrict__ grid, int n) {
    int i = blockIdx.x * blockDim.x + threadIdx.x;
    if (i < n) {
        int x = coords[i * 4], y = coords[i * 4 + 1], z = coords[i * 4 + 2];
        grid[(x << 16) | (y << 8) | z] = i;
    }
}

// F_input = LN(feats @ W_pre^T) ; accumulate stF into segment sums (atomics)
__launch_bounds__(256)
__global__ void k_pre(const void* __restrict__ feats,
                      const void* __restrict__ W_pre,
                      const void* __restrict__ ln_pre_w,
                      const void* __restrict__ ln_pre_b,
                      const void* __restrict__ W_pos,
                      const void* __restrict__ alpha,
                      const int* __restrict__ coords,
                      float* __restrict__ F_input,
                      float* __restrict__ sums,
                      float* __restrict__ counts,
                      const int* __restrict__ flag,
                      int n) {
    __shared__ float WT[64 * 64];  // WT[j*64+c] = W_pre[c][j]  (transposed: bank-conflict-free reads)
    const int f32m = *flag;
    for (int idx = threadIdx.x; idx < 4096; idx += blockDim.x) {
        int c = idx >> 6, j = idx & 63;
        WT[j * 64 + c] = ldf(W_pre, idx, f32m);
    }
    __syncthreads();

    const int wid = threadIdx.x >> 6;
    const int lane = threadIdx.x & 63;
    const int i = blockIdx.x * 4 + wid;
    if (i >= n) return;

    float f = ldf(feats, (size_t)i * 64 + lane, f32m);
    float acc = 0.f;
#pragma unroll
    for (int j = 0; j < 64; ++j)
        acc = fmaf(__shfl(f, j, 64), WT[j * 64 + lane], acc);

    // layernorm over the wave
    float m = wave_sum(acc) * (1.f / 64.f);
    float t = acc - m;
    float v = wave_sum(t * t) * (1.f / 64.f);
    float y = t * rsqrtf(v + EPSV) * ldf(ln_pre_w, lane, f32m) + ldf(ln_pre_b, lane, f32m);
    F_input[(size_t)i * 64 + lane] = y;

    int x = coords[i * 4], yy = coords[i * 4 + 1], z = coords[i * 4 + 2];
    float pos = ((float)x * ldf(W_pos, lane * 3 + 0, f32m) +
                 (float)yy * ldf(W_pos, lane * 3 + 1, f32m) +
                 (float)z * ldf(W_pos, lane * 3 + 2, f32m)) * ldf(alpha, lane, f32m);
    float sn = sinf(pos), cs = cosf(pos);

    int seg = (((x >> 3) << 5) + (yy >> 3)) * 32 + (z >> 3);
    float* sp = sums + (size_t)seg * 192;
    atomicAdd(sp + lane, y * cs);
    atomicAdd(sp + 64 + lane, y * sn);
    atomicAdd(sp + 128 + lane, y * pos);
    if (lane == 0) atomicAdd(counts + seg, 1.0f);
}

// vox gather + sparse 3x3x3 conv + two LNs + relu
__launch_bounds__(256)
__global__ void k_final(const void* __restrict__ feats,
                        const float* __restrict__ F_input,
                        const void* __restrict__ W_pos,
                        const void* __restrict__ alpha,
                        const void* __restrict__ conv_w,
                        const void* __restrict__ ln_w,
                        const void* __restrict__ ln_b,
                        const void* __restrict__ lnl_w,
                        const void* __restrict__ lnl_b,
                        const int* __restrict__ coords,
                        const int* __restrict__ grid,
                        const float* __restrict__ sums,
                        const float* __restrict__ counts,
                        void* __restrict__ out,
                        const int* __restrict__ flag,
                        int n) {
    const int f32m = *flag;
    const int wid = threadIdx.x >> 6;
    const int lane = threadIdx.x & 63;
    const int i = blockIdx.x * 4 + wid;
    if (i >= n) return;

    int x = coords[i * 4], y = coords[i * 4 + 1], z = coords[i * 4 + 2];
    float pos = ((float)x * ldf(W_pos, lane * 3 + 0, f32m) +
                 (float)y * ldf(W_pos, lane * 3 + 1, f32m) +
                 (float)z * ldf(W_pos, lane * 3 + 2, f32m)) * ldf(alpha, lane, f32m);
    float sn = sinf(pos), cs = cosf(pos);

    float F = F_input[(size_t)i * 64 + lane];
    float fw = F * pos;

    int seg = (((x >> 3) << 5) + (y >> 3)) * 32 + (z >> 3);
    float inv = 1.0f / fmaxf(counts[seg], 1.0f);
    const float* sp = sums + (size_t)seg * 192;
    float newF = sp[lane] * inv * cs + sp[64 + lane] * inv * sn + (sp[128 + lane] * inv - fw);

    // 27-neighbor probe: lanes 0..26 each test one offset
    int nidx = -1;
    if (lane < 27) {
        int dx = lane / 9 - 1, dy = (lane / 3) % 3 - 1, dz = lane % 3 - 1;
        int nx = x + dx, ny = y + dy, nz = z + dz;
        if (((unsigned)nx < 256u) && ((unsigned)ny < 256u) && ((unsigned)nz < 256u))
            nidx = grid[(nx << 16) | (ny << 8) | nz];
    }
    unsigned long long mask = __ballot(nidx >= 0);
    float local = 0.f;
    while (mask) {
        int k = __ffsll(mask) - 1;
        mask &= mask - 1;
        int pi = __shfl(nidx, k, 64);
        float g = ldf(feats, (size_t)pi * 64 + lane, f32m);
        const float* dummy = nullptr; (void)dummy;
#pragma unroll
        for (int j = 0; j < 64; ++j)
            local = fmaf(__shfl(g, j, 64), ldf(conv_w, ((size_t)k * 64 + j) * 64 + lane, f32m), local);
    }

    // LN(newF) + LN(local), relu
    float m1 = wave_sum(newF) * (1.f / 64.f);
    float t1 = newF - m1;
    float v1 = wave_sum(t1 * t1) * (1.f / 64.f);
    float a1 = t1 * rsqrtf(v1 + EPSV) * ldf(ln_w, lane, f32m) + ldf(ln_b, lane, f32m);

    float m2 = wave_sum(local) * (1.f / 64.f);
    float t2 = local - m2;
    float v2 = wave_sum(t2 * t2) * (1.f / 64.f);
    float a2 = t2 * rsqrtf(v2 + EPSV) * ldf(lnl_w, lane, f32m) + ldf(lnl_b, lane, f32m);

    float r = fmaxf(a1 + a2, 0.f);
    size_t o = (size_t)i * 64 + lane;
    if (f32m) ((float*)out)[o] = r;
    else ((unsigned short*)out)[o] = (unsigned short)((__float_as_uint(r) + 0x8000u +
                                     ((__float_as_uint(r) >> 16) & 1u)) >> 16);  // RNE bf16
}

extern "C" void kernel_launch(void* const* d_in, const int* in_sizes, int n_in,
                              void* d_out, int out_size, void* d_ws, size_t ws_size,
                              hipStream_t stream) {
    (void)n_in; (void)out_size; (void)ws_size;
    const void* feats   = d_in[0];
    const void* W_pre   = d_in[1];
    const void* ln_pre_w= d_in[2];
    const void* ln_pre_b= d_in[3];
    const void* W_pos   = d_in[4];
    const void* alpha   = d_in[5];
    const void* conv_w  = d_in[6];
    const void* ln_w    = d_in[7];
    const void* ln_b    = d_in[8];
    const void* lnl_w   = d_in[9];
    const void* lnl_b   = d_in[10];
    const int*  coords  = (const int*)d_in[11];

    const int n = in_sizes[0] / 64;

    char* ws = (char*)d_ws;
    int*   grid    = (int*)ws;                                   // 256^3*4 = 67,108,864 B
    size_t foff    = 67108864;
    float* F_input = (float*)(ws + foff);                        // n*64*4
    size_t soff    = foff + (size_t)n * 256;
    float* sums    = (float*)(ws + soff);                        // 32768*192*4 = 25,165,824 B
    size_t coff    = soff + 25165824;
    float* counts  = (float*)(ws + coff);                        // 32768*4
    int*   flag    = (int*)(ws + coff + 131072);

    hipMemsetAsync(grid, 0xFF, 67108864, stream);                // grid = -1
    hipMemsetAsync(sums, 0, 25165824 + 131072, stream);          // sums + counts = 0

    k_detect<<<1, 64, 0, stream>>>((const unsigned short*)feats, flag);
    k_scatter<<<(n + 255) / 256, 256, 0, stream>>>(coords, grid, n);
    k_pre<<<(n + 3) / 4, 256, 0, stream>>>(feats, W_pre, ln_pre_w, ln_pre_b, W_pos, alpha,
                                           coords, F_input, sums, counts, flag, n);
    k_final<<<(n + 3) / 4, 256, 0, stream>>>(feats, F_input, W_pos, alpha, conv_w,
                                             ln_w, ln_b, lnl_w, lnl_b, coords, grid,
                                             sums, counts, d_out, flag, n);
}

// Round 2
// 612.684 us; speedup vs baseline: 1.7181x; 1.7181x over previous
//
#include <hip/hip_runtime.h>

// ELKUNet forward on MI355X — round 2.
//  - No ds_bpermute anywhere: matvecs use weights-in-VGPRs + wave-uniform
//    scalar activation loads (readfirstlane-forced); LN reductions use DPP.
//  - No global atomics: segment sums via per-segment gather over the grid.
//  - Dense voxel grid (256^3 int32) for neighbor lookup.
//  - dtype probe retained (f32 vs bf16 device buffers), branch is uniform.

#define EPSV 1e-6f

__device__ __forceinline__ float ldf(const void* p, size_t idx, int f32m) {
    if (f32m) return ((const float*)p)[idx];
    unsigned int w = ((unsigned int)((const unsigned short*)p)[idx]) << 16;
    return __uint_as_float(w);
}

template <int CTRL, int RM>
__device__ __forceinline__ float dpp_add(float x) {
    int y = __builtin_amdgcn_update_dpp(0, __float_as_int(x), CTRL, RM, 0xf, true);
    return x + __int_as_float(y);
}

// full 64-lane sum, broadcast to all lanes. Pure VALU (DPP) + 1 readlane.
__device__ __forceinline__ float wave_sum(float x) {
    x = dpp_add<0xB1, 0xF>(x);   // quad_perm [1,0,3,2]  (xor 1)
    x = dpp_add<0x4E, 0xF>(x);   // quad_perm [2,3,0,1]  (xor 2)
    x = dpp_add<0x141, 0xF>(x);  // row_half_mirror      (xor 4)
    x = dpp_add<0x140, 0xF>(x);  // row_mirror           (xor 8)
    x = dpp_add<0x142, 0xA>(x);  // row_bcast:15 -> rows 1,3
    x = dpp_add<0x143, 0xC>(x);  // row_bcast:31 -> rows 2,3
    return __int_as_float(__builtin_amdgcn_readlane(__float_as_int(x), 63));
}

// dtype probe: f32 read as u16 -> even indices are mantissa halves with wild
// "exponent" bits; bf16 gaussians sit in a narrow exponent band.
__global__ void k_detect(const unsigned short* __restrict__ u, int* __restrict__ flag) {
    if (threadIdx.x != 0) return;
    int wild = 0;
    for (int k = 0; k < 2048; ++k) {
        int e = (u[2 * k] >> 7) & 0xFF;
        if (e > 140 || (e < 100 && e != 0)) wild++;
    }
    *flag = (wild > 200) ? 1 : 0;  // 1 => f32 mode
}

__global__ void k_scatter(const int* __restrict__ coords, int* __restrict__ grid, int n) {
    int i = blockIdx.x * blockDim.x + threadIdx.x;
    if (i < n) {
        int x = coords[i * 4], y = coords[i * 4 + 1], z = coords[i * 4 + 2];
        grid[(x << 16) | (y << 8) | z] = i;
    }
}

// F_input = LN(feats @ W_pre^T). Persistent waves; W row in VGPRs; feats row
// loaded wave-uniform (scalarizable); zero cross-lane data movement.
__launch_bounds__(256)
__global__ void k_pre(const void* __restrict__ feats,
                      const void* __restrict__ W_pre,
                      const void* __restrict__ ln_pre_w,
                      const void* __restrict__ ln_pre_b,
                      float* __restrict__ F_input,
                      const int* __restrict__ flag,
                      int n, int nwaves) {
    const int f32m = *flag;
    const int lane = threadIdx.x & 63;
    const int wave = (blockIdx.x * blockDim.x + threadIdx.x) >> 6;

    float W[64];  // W_pre[lane][j]
    if (f32m) {
        const float4* wr = (const float4*)W_pre + lane * 16;
#pragma unroll
        for (int q = 0; q < 16; ++q) {
            float4 w4 = wr[q];
            W[4*q] = w4.x; W[4*q+1] = w4.y; W[4*q+2] = w4.z; W[4*q+3] = w4.w;
        }
    } else {
#pragma unroll
        for (int j = 0; j < 64; ++j) W[j] = ldf(W_pre, lane * 64 + j, 0);
    }
    const float lw = ldf(ln_pre_w, lane, f32m);
    const float lb = ldf(ln_pre_b, lane, f32m);

    for (int i = wave; i < n; i += nwaves) {
        const int si = __builtin_amdgcn_readfirstlane(i);
        float acc = 0.f;
        if (f32m) {
            const float4* fr = (const float4*)feats + (size_t)si * 16;
#pragma unroll
            for (int q = 0; q < 16; ++q) {
                float4 f4 = fr[q];
                acc = fmaf(f4.x, W[4*q], acc);
                acc = fmaf(f4.y, W[4*q+1], acc);
                acc = fmaf(f4.z, W[4*q+2], acc);
                acc = fmaf(f4.w, W[4*q+3], acc);
            }
        } else {
            const unsigned short* fr = (const unsigned short*)feats + (size_t)si * 64;
#pragma unroll
            for (int j = 0; j < 64; ++j)
                acc = fmaf(__uint_as_float((unsigned)fr[j] << 16), W[j], acc);
        }
        float m = wave_sum(acc) * (1.f / 64.f);
        float t = acc - m;
        float v = wave_sum(t * t) * (1.f / 64.f);
        F_input[(size_t)si * 64 + lane] = t * rsqrtf(v + EPSV) * lw + lb;
    }
}

// Segment sums by gather: 1 wave = 1 segment; scan 512 cells, recover point
// coords from the cell index (cells are unique per point), accumulate stF.
__launch_bounds__(256)
__global__ void k_seg(const float* __restrict__ F_input,
                      const int* __restrict__ grid,
                      const void* __restrict__ W_pos,
                      const void* __restrict__ alpha,
                      float* __restrict__ sums,
                      float* __restrict__ counts,
                      const int* __restrict__ flag) {
    const int f32m = *flag;
    const int lane = threadIdx.x & 63;
    const int seg = (blockIdx.x << 2) + (threadIdx.x >> 6);
    const int cx = seg >> 10, cy = (seg >> 5) & 31, cz = seg & 31;

    const float wx = ldf(W_pos, lane * 3 + 0, f32m);
    const float wy = ldf(W_pos, lane * 3 + 1, f32m);
    const float wz = ldf(W_pos, lane * 3 + 2, f32m);
    const float al = ldf(alpha, lane, f32m);

    float aC = 0.f, aS = 0.f, aL = 0.f;
    int cnt = 0;
#pragma unroll
    for (int it = 0; it < 8; ++it) {
        int c = (it << 6) | lane;                       // cell within segment [0,512)
        int dx = c >> 6, dy = (c >> 3) & 7, dz = c & 7;
        int addr = (((cx << 3) + dx) << 16) | (((cy << 3) + dy) << 8) | ((cz << 3) + dz);
        int idx = grid[addr];
        unsigned long long mask = __ballot(idx >= 0);
        cnt += __popcll(mask);
        while (mask) {
            int b = __ffsll(mask) - 1;
            mask &= mask - 1;
            int pi = __builtin_amdgcn_readlane(idx, b);
            int cb = (it << 6) | b;
            int px = (cx << 3) + (cb >> 6);
            int py = (cy << 3) + ((cb >> 3) & 7);
            int pz = (cz << 3) + (cb & 7);
            float F = F_input[(size_t)pi * 64 + lane];
            float pos = ((float)px * wx + (float)py * wy + (float)pz * wz) * al;
            float sn = sinf(pos), cs = cosf(pos);
            aC = fmaf(F, cs, aC);
            aS = fmaf(F, sn, aS);
            aL = fmaf(F, pos, aL);
        }
    }
    float* sp = sums + (size_t)seg * 192;
    sp[lane] = aC;
    sp[64 + lane] = aS;
    sp[128 + lane] = aL;
    if (lane == 0) counts[seg] = (float)cnt;
}

// vox gather + self-conv (in-register) + rare-neighbor conv + two LNs + relu
__launch_bounds__(256)
__global__ void k_final(const void* __restrict__ feats,
                        const float* __restrict__ F_input,
                        const void* __restrict__ W_pos,
                        const void* __restrict__ alpha,
                        const void* __restrict__ conv_w,
                        const void* __restrict__ ln_w,
                        const void* __restrict__ ln_b,
                        const void* __restrict__ lnl_w,
                        const void* __restrict__ lnl_b,
                        const int* __restrict__ coords,
                        const int* __restrict__ grid,
                        const float* __restrict__ sums,
                        const float* __restrict__ counts,
                        void* __restrict__ out,
                        const int* __restrict__ flag,
                        int n, int nwaves) {
    const int f32m = *flag;
    const int lane = threadIdx.x & 63;
    const int wave = (blockIdx.x * blockDim.x + threadIdx.x) >> 6;

    float W13[64];  // conv_w[13][j][lane]
#pragma unroll
    for (int j = 0; j < 64; ++j)
        W13[j] = ldf(conv_w, ((size_t)(13 * 64 + j)) * 64 + lane, f32m);

    const float wx = ldf(W_pos, lane * 3 + 0, f32m);
    const float wy = ldf(W_pos, lane * 3 + 1, f32m);
    const float wz = ldf(W_pos, lane * 3 + 2, f32m);
    const float al = ldf(alpha, lane, f32m);
    const float lnwv = ldf(ln_w, lane, f32m), lnbv = ldf(ln_b, lane, f32m);
    const float llwv = ldf(lnl_w, lane, f32m), llbv = ldf(lnl_b, lane, f32m);

    for (int i = wave; i < n; i += nwaves) {
        const int si = __builtin_amdgcn_readfirstlane(i);
        int x = coords[si * 4], y = coords[si * 4 + 1], z = coords[si * 4 + 2];
        float pos = ((float)x * wx + (float)y * wy + (float)z * wz) * al;
        float sn = sinf(pos), cs = cosf(pos);

        float F = F_input[(size_t)si * 64 + lane];
        float fw = F * pos;

        int seg = (((x >> 3) << 5) + (y >> 3)) * 32 + (z >> 3);
        float inv = 1.0f / fmaxf(counts[seg], 1.0f);
        const float* sp = sums + (size_t)seg * 192;
        float newF = fmaf(sp[lane] * inv, cs,
                     fmaf(sp[64 + lane] * inv, sn, sp[128 + lane] * inv - fw));

        // self conv (k=13, always valid): in-register weights, uniform g loads
        float local = 0.f;
        if (f32m) {
            const float4* gr = (const float4*)feats + (size_t)si * 16;
#pragma unroll
            for (int q = 0; q < 16; ++q) {
                float4 g4 = gr[q];
                local = fmaf(g4.x, W13[4*q], local);
                local = fmaf(g4.y, W13[4*q+1], local);
                local = fmaf(g4.z, W13[4*q+2], local);
                local = fmaf(g4.w, W13[4*q+3], local);
            }
        } else {
            const unsigned short* gr = (const unsigned short*)feats + (size_t)si * 64;
#pragma unroll
            for (int j = 0; j < 64; ++j)
                local = fmaf(__uint_as_float((unsigned)gr[j] << 16), W13[j], local);
        }

        // rare non-self neighbors (~0.31/point expected)
        int nidx = -1;
        if (lane < 27 && lane != 13) {
            int dx = lane / 9 - 1, dy = (lane / 3) % 3 - 1, dz = lane % 3 - 1;
            int nx = x + dx, ny = y + dy, nz = z + dz;
            if (((unsigned)nx < 256u) && ((unsigned)ny < 256u) && ((unsigned)nz < 256u))
                nidx = grid[(nx << 16) | (ny << 8) | nz];
        }
        unsigned long long mask = __ballot(nidx >= 0);
        while (mask) {
            int k = __ffsll(mask) - 1;
            mask &= mask - 1;
            int pi = __builtin_amdgcn_readlane(nidx, k);
            if (f32m) {
                const float4* gr = (const float4*)feats + (size_t)pi * 16;
                const float* cw = (const float*)conv_w + (size_t)k * 4096;
#pragma unroll
                for (int q = 0; q < 16; ++q) {
                    float4 g4 = gr[q];
                    local = fmaf(g4.x, cw[(4*q    ) * 64 + lane], local);
                    local = fmaf(g4.y, cw[(4*q + 1) * 64 + lane], local);
                    local = fmaf(g4.z, cw[(4*q + 2) * 64 + lane], local);
                    local = fmaf(g4.w, cw[(4*q + 3) * 64 + lane], local);
                }
            } else {
                const unsigned short* gr = (const unsigned short*)feats + (size_t)pi * 64;
#pragma unroll
                for (int j = 0; j < 64; ++j)
                    local = fmaf(__uint_as_float((unsigned)gr[j] << 16),
                                 ldf(conv_w, ((size_t)(k * 64 + j)) * 64 + lane, 0), local);
            }
        }

        float m1 = wave_sum(newF) * (1.f / 64.f);
        float t1 = newF - m1;
        float v1 = wave_sum(t1 * t1) * (1.f / 64.f);
        float a1 = t1 * rsqrtf(v1 + EPSV) * lnwv + lnbv;

        float m2 = wave_sum(local) * (1.f / 64.f);
        float t2 = local - m2;
        float v2 = wave_sum(t2 * t2) * (1.f / 64.f);
        float a2 = t2 * rsqrtf(v2 + EPSV) * llwv + llbv;

        float r = fmaxf(a1 + a2, 0.f);
        size_t o = (size_t)si * 64 + lane;
        if (f32m) ((float*)out)[o] = r;
        else ((unsigned short*)out)[o] = (unsigned short)((__float_as_uint(r) + 0x8000u +
                                         ((__float_as_uint(r) >> 16) & 1u)) >> 16);
    }
}

extern "C" void kernel_launch(void* const* d_in, const int* in_sizes, int n_in,
                              void* d_out, int out_size, void* d_ws, size_t ws_size,
                              hipStream_t stream) {
    (void)n_in; (void)out_size; (void)ws_size;
    const void* feats    = d_in[0];
    const void* W_pre    = d_in[1];
    const void* ln_pre_w = d_in[2];
    const void* ln_pre_b = d_in[3];
    const void* W_pos    = d_in[4];
    const void* alpha    = d_in[5];
    const void* conv_w   = d_in[6];
    const void* ln_w     = d_in[7];
    const void* ln_b     = d_in[8];
    const void* lnl_w    = d_in[9];
    const void* lnl_b    = d_in[10];
    const int*  coords   = (const int*)d_in[11];

    const int n = in_sizes[0] / 64;

    char* ws = (char*)d_ws;
    int*   grid    = (int*)ws;                       // 256^3*4 = 67,108,864 B
    size_t foff    = 67108864;
    float* F_input = (float*)(ws + foff);            // n*64*4
    size_t soff    = foff + (size_t)n * 256;
    float* sums    = (float*)(ws + soff);            // 32768*192*4
    size_t coff    = soff + 25165824;
    float* counts  = (float*)(ws + coff);            // 32768*4
    int*   flag    = (int*)(ws + coff + 131072);

    hipMemsetAsync(grid, 0xFF, 67108864, stream);    // grid = -1

    k_detect<<<1, 64, 0, stream>>>((const unsigned short*)feats, flag);
    k_scatter<<<(n + 255) / 256, 256, 0, stream>>>(coords, grid, n);

    const int preBlocks = 1024;                      // 4096 waves
    k_pre<<<preBlocks, 256, 0, stream>>>(feats, W_pre, ln_pre_w, ln_pre_b,
                                         F_input, flag, n, preBlocks * 4);
    k_seg<<<8192, 256, 0, stream>>>(F_input, grid, W_pos, alpha, sums, counts, flag);

    const int finBlocks = 2048;                      // 8192 waves
    k_final<<<finBlocks, 256, 0, stream>>>(feats, F_input, W_pos, alpha, conv_w,
                                           ln_w, ln_b, lnl_w, lnl_b, coords, grid,
                                           sums, counts, d_out, flag, n, finBlocks * 4);
}

// Round 4
// 428.350 us; speedup vs baseline: 2.4575x; 1.4303x over previous
//
#include <hip/hip_runtime.h>

// ELKUNet forward on MI355X — round 4.
// Device tensors are FLOAT32 (proved live: rounds 1-2 passed with the runtime
// dtype probe selecting f32; round-3's bf16 assumption failed with stub-level
// error). f32 hard-coded now.
//  - 2MB occupancy bitmap (L2-resident) replaces 26 random grid probes/pt;
//    grid (67MB) read only at set bits -> no grid memset.
//  - Self-conv (k=13, always valid) computed in k_pre where the feats row is
//    already in registers; k_final's critical path loses 128 FMA + row load.
//  - LN reductions via DPP (zero LDS traffic); __sinf/__cosf; coords prefetch.

typedef unsigned int u32;
typedef unsigned long long u64;

#define EPSV 1e-6f

template<int C,int R> __device__ __forceinline__ float dpp_add(float x){
    int y = __builtin_amdgcn_update_dpp(0, __float_as_int(x), C, R, 0xf, true);
    return x + __int_as_float(y);
}
// full 64-lane sum broadcast to all lanes; pure VALU + 1 readlane.
__device__ __forceinline__ float wave_sum(float x){
    x = dpp_add<0xB1,0xF>(x);   // xor 1
    x = dpp_add<0x4E,0xF>(x);   // xor 2
    x = dpp_add<0x141,0xF>(x);  // xor 4
    x = dpp_add<0x140,0xF>(x);  // xor 8
    x = dpp_add<0x142,0xA>(x);  // row_bcast:15
    x = dpp_add<0x143,0xC>(x);  // row_bcast:31
    return __int_as_float(__builtin_amdgcn_readlane(__float_as_int(x), 63));
}

__global__ void k_scatter(const int* __restrict__ coords, int* __restrict__ grid,
                          u32* __restrict__ bm, int n){
    int i = blockIdx.x * blockDim.x + threadIdx.x;
    if(i < n){
        int x = coords[i*4], y = coords[i*4+1], z = coords[i*4+2];
        int b = (x << 16) | (y << 8) | z;
        grid[b] = i;
        atomicOr(&bm[b >> 5], 1u << (b & 31));
    }
}

// F_input = LN(feats @ W_pre^T); selfconv = feats @ conv_w[13] (if SC).
template<bool SC>
__launch_bounds__(256)
__global__ void k_pre(const float* __restrict__ feats, const float* __restrict__ W_pre,
                      const float* __restrict__ lnw, const float* __restrict__ lnb,
                      const float* __restrict__ conv_w,
                      float* __restrict__ F_input, float* __restrict__ selfconv,
                      int n, int nwaves){
    const int lane = threadIdx.x & 63;
    const int wave = (blockIdx.x * blockDim.x + threadIdx.x) >> 6;

    float W[64];   // W_pre[lane][j]
    {   const float4* wr = (const float4*)(W_pre + (size_t)lane * 64);
#pragma unroll
        for(int q = 0; q < 16; ++q){
            float4 v = wr[q];
            W[4*q] = v.x; W[4*q+1] = v.y; W[4*q+2] = v.z; W[4*q+3] = v.w;
        }
    }
    float W13[64]; // conv_w[13][j][lane]
    if(SC){
#pragma unroll
        for(int j = 0; j < 64; ++j) W13[j] = conv_w[(13*64 + j)*64 + lane];
    }
    const float lw = lnw[lane], lb = lnb[lane];

    for(int i = wave; i < n; i += nwaves){
        const int si = __builtin_amdgcn_readfirstlane(i);
        const float4* fr = (const float4*)(feats + (size_t)si * 64);
        float a0=0.f, a1=0.f, a2=0.f, a3=0.f;
        float s0=0.f, s1=0.f, s2=0.f, s3=0.f;
#pragma unroll
        for(int q = 0; q < 16; ++q){
            float4 f = fr[q];
            a0 = fmaf(f.x, W[4*q],   a0);
            a1 = fmaf(f.y, W[4*q+1], a1);
            a2 = fmaf(f.z, W[4*q+2], a2);
            a3 = fmaf(f.w, W[4*q+3], a3);
            if(SC){
                s0 = fmaf(f.x, W13[4*q],   s0);
                s1 = fmaf(f.y, W13[4*q+1], s1);
                s2 = fmaf(f.z, W13[4*q+2], s2);
                s3 = fmaf(f.w, W13[4*q+3], s3);
            }
        }
        float acc = (a0 + a1) + (a2 + a3);
        float m = wave_sum(acc) * (1.f/64.f);
        float t = acc - m;
        float v = wave_sum(t*t) * (1.f/64.f);
        F_input[(size_t)si*64 + lane] = t * rsqrtf(v + EPSV) * lw + lb;
        if(SC) selfconv[(size_t)si*64 + lane] = (s0 + s1) + (s2 + s3);
    }
}

// Segment sums by gather: 1 wave = 1 segment; bitmap gives occupied cells.
__launch_bounds__(256)
__global__ void k_seg(const float* __restrict__ F_input, const int* __restrict__ grid,
                      const u64* __restrict__ bm, const float* __restrict__ W_pos,
                      const float* __restrict__ alpha,
                      float* __restrict__ sums, float* __restrict__ counts){
    const int lane = threadIdx.x & 63;
    const int seg = (blockIdx.x << 2) + (threadIdx.x >> 6);
    const int cx = seg >> 10, cy = (seg >> 5) & 31, cz = seg & 31;

    const int px0 = (cx << 3) + (lane >> 3), py0 = (cy << 3) + (lane & 7);
    u64 w = bm[((size_t)px0 << 10) | ((u32)py0 << 2) | (u32)(cz >> 3)];
    u32 occ8 = (u32)(w >> ((cz & 7) * 8)) & 0xffu;
    float cnt = wave_sum((float)__popc(occ8));

    const float wx = W_pos[lane*3+0], wy = W_pos[lane*3+1], wz = W_pos[lane*3+2];
    const float al = alpha[lane];

    float aC = 0.f, aS = 0.f, aL = 0.f;
    u64 m = __ballot(occ8 != 0u);
    while(m){
        int l = __ffsll(m) - 1; m &= m - 1;
        u32 o8 = (u32)__builtin_amdgcn_readlane((int)occ8, l);
        int px = (cx << 3) + (l >> 3), py = (cy << 3) + (l & 7);
        while(o8){
            int dz = __ffs(o8) - 1; o8 &= o8 - 1;
            int pz = (cz << 3) + dz;
            int pi = grid[(px << 16) | (py << 8) | pz];
            float F = F_input[(size_t)pi*64 + lane];
            float pos = ((float)px*wx + (float)py*wy + (float)pz*wz) * al;
            aC = fmaf(F, __cosf(pos), aC);
            aS = fmaf(F, __sinf(pos), aS);
            aL = fmaf(F, pos, aL);
        }
    }
    float* sp = sums + (size_t)seg * 192;
    sp[lane] = aC; sp[64 + lane] = aS; sp[128 + lane] = aL;
    if(lane == 0) counts[seg] = cnt;
}

template<bool SC>
__launch_bounds__(256)
__global__ void k_final(const float* __restrict__ feats,
                        const float* __restrict__ F_input,
                        const float* __restrict__ selfconv,
                        const float* __restrict__ W_pos, const float* __restrict__ alpha,
                        const float* __restrict__ conv_w,
                        const float* __restrict__ ln_w, const float* __restrict__ ln_b,
                        const float* __restrict__ lnl_w, const float* __restrict__ lnl_b,
                        const int* __restrict__ coords, const int* __restrict__ grid,
                        const u64* __restrict__ bm,
                        const float* __restrict__ sums, const float* __restrict__ counts,
                        float* __restrict__ out, int n, int nwaves){
    const int lane = threadIdx.x & 63;
    const int wave = (blockIdx.x * blockDim.x + threadIdx.x) >> 6;

    const float wx = W_pos[lane*3+0], wy = W_pos[lane*3+1], wz = W_pos[lane*3+2];
    const float al = alpha[lane];
    const float lnwv = ln_w[lane], lnbv = ln_b[lane];
    const float llwv = lnl_w[lane], llbv = lnl_b[lane];

    float W13[64];
    if(!SC){
#pragma unroll
        for(int j = 0; j < 64; ++j) W13[j] = conv_w[(13*64 + j)*64 + lane];
    }

    int i = wave;
    int4 crd = make_int4(0,0,0,0);
    if(i < n) crd = ((const int4*)coords)[__builtin_amdgcn_readfirstlane(i)];

    for(; i < n; i += nwaves){
        const int si = __builtin_amdgcn_readfirstlane(i);
        const int x = crd.x, y = crd.y, z = crd.z;
        const int seg = ((x >> 3) << 10) | ((y >> 3) << 5) | (z >> 3);

        // issue all independent loads up front
        const float* sp = sums + (size_t)seg * 192;
        float s0 = sp[lane], s1v = sp[64 + lane], s2v = sp[128 + lane];
        float cntv = counts[seg];
        float F = F_input[(size_t)si*64 + lane];
        float local = 0.f;
        float4 SA[16];
        if(SC) local = selfconv[(size_t)si*64 + lane];
        else {
            const float4* fa = (const float4*)(feats + (size_t)si * 64);
#pragma unroll
            for(int q = 0; q < 16; ++q) SA[q] = fa[q];
        }

        // bitmap probe: lanes 0..8 cover (dx,dy); 3 z-bits each
        u32 m3 = 0;
        if(lane < 9){
            int nx = x + lane/3 - 1, ny = y + lane%3 - 1;
            if(((u32)nx < 256u) && ((u32)ny < 256u)){
                const u64* wp = bm + (((size_t)nx << 10) | ((u32)ny << 2));
                int zb = z & 63;
                if(zb >= 1 && zb <= 62){
                    u64 w = wp[z >> 6];
                    m3 = (u32)((w >> (zb - 1)) & 7ull);
                } else {
#pragma unroll
                    for(int t = 0; t < 3; ++t){
                        int zz = z + t - 1;
                        if((u32)zz < 256u){
                            u64 w = wp[zz >> 6];
                            m3 |= (u32)((w >> (zz & 63)) & 1ull) << t;
                        }
                    }
                }
            }
        }
        u64 b0 = __ballot(m3 & 1u);
        u64 b1 = __ballot(m3 & 2u) & ~(1ull << 4);   // drop self (l=4 -> dx=dy=0, t=1 -> dz=0)
        u64 b2 = __ballot(m3 & 4u);

        // prefetch next coords
        const int inext = i + nwaves;
        if(inext < n) crd = ((const int4*)coords)[__builtin_amdgcn_readfirstlane(inext)];

        float pos = ((float)x*wx + (float)y*wy + (float)z*wz) * al;
        float sn = __sinf(pos), cs = __cosf(pos);
        float fw = F * pos;
        float inv = 1.f / fmaxf(cntv, 1.f);
        float newF = fmaf(s0*inv, cs, fmaf(s1v*inv, sn, s2v*inv - fw));

        if(!SC){
#pragma unroll
            for(int q = 0; q < 16; ++q){
                float4 g = SA[q];
                local = fmaf(g.x, W13[4*q],   local);
                local = fmaf(g.y, W13[4*q+1], local);
                local = fmaf(g.z, W13[4*q+2], local);
                local = fmaf(g.w, W13[4*q+3], local);
            }
        }

        // rare non-self neighbors (~0.31/pt expected)
#pragma unroll
        for(int t = 0; t < 3; ++t){
            u64 m = (t == 0) ? b0 : ((t == 1) ? b1 : b2);
            while(m){
                int l2 = __ffsll(m) - 1; m &= m - 1;
                int nx = x + l2/3 - 1, ny = y + l2%3 - 1, nz = z + t - 1;
                int k = 3*l2 + t;
                int pi = grid[(nx << 16) | (ny << 8) | nz];
                const float4* gv = (const float4*)(feats + (size_t)pi * 64);
                const float* cw = conv_w + (size_t)k * 4096;
#pragma unroll
                for(int q = 0; q < 16; ++q){
                    float4 g = gv[q];
                    local = fmaf(g.x, cw[(4*q    ) * 64 + lane], local);
                    local = fmaf(g.y, cw[(4*q + 1) * 64 + lane], local);
                    local = fmaf(g.z, cw[(4*q + 2) * 64 + lane], local);
                    local = fmaf(g.w, cw[(4*q + 3) * 64 + lane], local);
                }
            }
        }

        float m1 = wave_sum(newF) * (1.f/64.f);
        float t1 = newF - m1;
        float v1 = wave_sum(t1*t1) * (1.f/64.f);
        float a1 = t1 * rsqrtf(v1 + EPSV) * lnwv + lnbv;

        float m2 = wave_sum(local) * (1.f/64.f);
        float t2 = local - m2;
        float v2 = wave_sum(t2*t2) * (1.f/64.f);
        float a2 = t2 * rsqrtf(v2 + EPSV) * llwv + llbv;

        out[(size_t)si*64 + lane] = fmaxf(a1 + a2, 0.f);
    }
}

extern "C" void kernel_launch(void* const* d_in, const int* in_sizes, int n_in,
                              void* d_out, int out_size, void* d_ws, size_t ws_size,
                              hipStream_t stream) {
    (void)n_in; (void)out_size;
    const float* feats    = (const float*)d_in[0];
    const float* W_pre    = (const float*)d_in[1];
    const float* ln_pre_w = (const float*)d_in[2];
    const float* ln_pre_b = (const float*)d_in[3];
    const float* W_pos    = (const float*)d_in[4];
    const float* alpha    = (const float*)d_in[5];
    const float* conv_w   = (const float*)d_in[6];
    const float* ln_w     = (const float*)d_in[7];
    const float* ln_b     = (const float*)d_in[8];
    const float* lnl_w    = (const float*)d_in[9];
    const float* lnl_b    = (const float*)d_in[10];
    const int*   coords   = (const int*)d_in[11];

    const int n = in_sizes[0] / 64;

    char* ws = (char*)d_ws;
    u32* bm32      = (u32*)ws;                         // 2,097,152 B
    u64* bm64      = (u64*)ws;
    int* grid      = (int*)(ws + 2097152);             // 67,108,864 B (no memset: bitmap gates reads)
    float* F_input = (float*)(ws + 69206016);          // n*256 B
    size_t off = 69206016 + (size_t)n * 256;
    float* sums    = (float*)(ws + off); off += 25165824;
    float* counts  = (float*)(ws + off); off += 131072;
    float* selfconv = (float*)(ws + off);
    const bool sc = ws_size >= off + (size_t)n * 256;

    hipMemsetAsync(bm32, 0, 2097152, stream);
    k_scatter<<<(n + 255)/256, 256, 0, stream>>>(coords, grid, bm32, n);

    if(sc) k_pre<true ><<<1024, 256, 0, stream>>>(feats, W_pre, ln_pre_w, ln_pre_b, conv_w,
                                                  F_input, selfconv, n, 4096);
    else   k_pre<false><<<1024, 256, 0, stream>>>(feats, W_pre, ln_pre_w, ln_pre_b, conv_w,
                                                  F_input, selfconv, n, 4096);

    k_seg<<<8192, 256, 0, stream>>>(F_input, grid, bm64, W_pos, alpha, sums, counts);

    if(sc) k_final<true ><<<2048, 256, 0, stream>>>(feats, F_input, selfconv, W_pos, alpha, conv_w,
                                                    ln_w, ln_b, lnl_w, lnl_b, coords, grid, bm64,
                                                    sums, counts, (float*)d_out, n, 8192);
    else   k_final<false><<<2048, 256, 0, stream>>>(feats, F_input, selfconv, W_pos, alpha, conv_w,
                                                    ln_w, ln_b, lnl_w, lnl_b, coords, grid, bm64,
                                                    sums, counts, (float*)d_out, n, 8192);
}

// Round 5
// 341.150 us; speedup vs baseline: 3.0856x; 1.2556x over previous
//
#include <hip/hip_runtime.h>

// ELKUNet forward on MI355X — round 5. f32 device tensors (proven live r1/r2/r4).
// Pipeline: memset(hash=FF, bm/sums/counts/nbrcnt=0) -> k_scatter (bitmap +
// cell->pi hash) -> k_nbr (per-(pt,dir) lane-parallel neighbor lists) ->
// k_pre (LN matvec + selfconv + segment sums via atomics) -> k_final
// (software-pipelined: prefetch pt i+1 while computing pt i).
//  - 8MB hash replaces 67MB dense grid; 2MB bitmap gates all lookups.
//  - k_seg eliminated (atomics in k_pre) -> saves 51MB F re-read + a launch.
//  - ws total 145.4MB <= 145.7MB proven available in rounds 2/4.

typedef unsigned int u32;
typedef unsigned long long u64;

#define EPSV 1e-6f
#define HBITS 20
#define HSIZE (1u << HBITS)
#define HMASK (HSIZE - 1u)

template<int C,int R> __device__ __forceinline__ float dpp_add(float x){
    int y = __builtin_amdgcn_update_dpp(0, __float_as_int(x), C, R, 0xf, true);
    return x + __int_as_float(y);
}
// full 64-lane sum broadcast to all lanes; pure VALU + 1 readlane.
__device__ __forceinline__ float wave_sum(float x){
    x = dpp_add<0xB1,0xF>(x);   // xor 1
    x = dpp_add<0x4E,0xF>(x);   // xor 2
    x = dpp_add<0x141,0xF>(x);  // xor 4
    x = dpp_add<0x140,0xF>(x);  // xor 8
    x = dpp_add<0x142,0xA>(x);  // row_bcast:15
    x = dpp_add<0x143,0xC>(x);  // row_bcast:31
    return __int_as_float(__builtin_amdgcn_readlane(__float_as_int(x), 63));
}

__device__ __forceinline__ u32 hslot(u32 b){ return (b * 0x9E3779B1u) >> (32 - HBITS); }

__global__ void k_scatter(const int* __restrict__ coords, u64* __restrict__ hash,
                          u32* __restrict__ bm, int n){
    int i = blockIdx.x * blockDim.x + threadIdx.x;
    if(i < n){
        int4 c = ((const int4*)coords)[i];
        u32 b = ((u32)c.x << 16) | ((u32)c.y << 8) | (u32)c.z;
        atomicOr(&bm[b >> 5], 1u << (b & 31));
        u64 entry = ((u64)b << 32) | (u32)i;
        u32 s = hslot(b);
        while(atomicCAS(&hash[s], ~0ull, entry) != ~0ull) s = (s + 1) & HMASK;
    }
}

// 1 thread per (point, direction): bitmap probe -> hash lookup -> append list.
__global__ void k_nbr(const int* __restrict__ coords, const u64* __restrict__ hash,
                      const u32* __restrict__ bm, u32* __restrict__ nbrcnt,
                      u32* __restrict__ nbrlst, int n){
    int t = blockIdx.x * blockDim.x + threadIdx.x;
    int pt = t / 27;
    if(pt >= n) return;
    int d = t - pt * 27;
    if(d == 13) return;                          // self handled densely in k_pre
    int4 c = ((const int4*)coords)[pt];
    int nx = c.x + d / 9 - 1, ny = c.y + (d / 3) % 3 - 1, nz = c.z + d % 3 - 1;
    if(((u32)nx >= 256u) | ((u32)ny >= 256u) | ((u32)nz >= 256u)) return;
    u32 b = ((u32)nx << 16) | ((u32)ny << 8) | (u32)nz;
    if(!((bm[b >> 5] >> (b & 31)) & 1u)) return;
    u32 s = hslot(b);
    u64 e;
    while((u32)((e = hash[s]) >> 32) != b) s = (s + 1) & HMASK;
    u32 slot = atomicAdd(&nbrcnt[pt], 1u);
    if(slot < 8u) nbrlst[(size_t)pt * 8 + slot] = ((u32)d << 25) | (u32)e;
}

// F_input = LN(feats @ W_pre^T); selfconv = feats @ conv_w[13];
// segment sums of {F*cos, F*sin, F*pos} + counts via atomics.
__launch_bounds__(256)
__global__ void k_pre(const float* __restrict__ feats, const float* __restrict__ W_pre,
                      const float* __restrict__ lnw, const float* __restrict__ lnb,
                      const float* __restrict__ conv_w,
                      const float* __restrict__ W_pos, const float* __restrict__ alpha,
                      const int* __restrict__ coords,
                      float* __restrict__ F_input, float* __restrict__ selfconv,
                      float* __restrict__ sums, float* __restrict__ counts,
                      int n, int nwaves){
    const int lane = threadIdx.x & 63;
    const int wave = (blockIdx.x * blockDim.x + threadIdx.x) >> 6;

    float W[64];   // W_pre[lane][j]
    {   const float4* wr = (const float4*)(W_pre + (size_t)lane * 64);
#pragma unroll
        for(int q = 0; q < 16; ++q){
            float4 v = wr[q];
            W[4*q] = v.x; W[4*q+1] = v.y; W[4*q+2] = v.z; W[4*q+3] = v.w;
        }
    }
    float W13[64]; // conv_w[13][j][lane]
#pragma unroll
    for(int j = 0; j < 64; ++j) W13[j] = conv_w[(13*64 + j)*64 + lane];

    const float lw = lnw[lane], lb = lnb[lane];
    const float wx = W_pos[lane*3+0], wy = W_pos[lane*3+1], wz = W_pos[lane*3+2];
    const float al = alpha[lane];

    for(int i = wave; i < n; i += nwaves){
        const int si = __builtin_amdgcn_readfirstlane(i);
        const int4 c = ((const int4*)coords)[si];
        const float4* fr = (const float4*)(feats + (size_t)si * 64);
        float a0=0.f, a1=0.f, a2=0.f, a3=0.f;
        float s0=0.f, s1=0.f, s2=0.f, s3=0.f;
#pragma unroll
        for(int q = 0; q < 16; ++q){
            float4 f = fr[q];
            a0 = fmaf(f.x, W[4*q],   a0);
            a1 = fmaf(f.y, W[4*q+1], a1);
            a2 = fmaf(f.z, W[4*q+2], a2);
            a3 = fmaf(f.w, W[4*q+3], a3);
            s0 = fmaf(f.x, W13[4*q],   s0);
            s1 = fmaf(f.y, W13[4*q+1], s1);
            s2 = fmaf(f.z, W13[4*q+2], s2);
            s3 = fmaf(f.w, W13[4*q+3], s3);
        }
        float acc = (a0 + a1) + (a2 + a3);
        float m = wave_sum(acc) * (1.f/64.f);
        float t = acc - m;
        float v = wave_sum(t*t) * (1.f/64.f);
        float y = t * rsqrtf(v + EPSV) * lw + lb;
        F_input[(size_t)si*64 + lane] = y;
        selfconv[(size_t)si*64 + lane] = (s0 + s1) + (s2 + s3);

        float pos = ((float)c.x*wx + (float)c.y*wy + (float)c.z*wz) * al;
        int seg = ((c.x >> 3) << 10) | ((c.y >> 3) << 5) | (c.z >> 3);
        float* sp = sums + (size_t)seg * 192;
        atomicAdd(sp + lane,        y * __cosf(pos));
        atomicAdd(sp + 64 + lane,   y * __sinf(pos));
        atomicAdd(sp + 128 + lane,  y * pos);
        if(lane == 0) atomicAdd(counts + seg, 1.0f);
    }
}

// Software-pipelined final: prefetch point i+1's loads while computing point i.
__launch_bounds__(256)
__global__ void k_final(const float* __restrict__ feats,
                        const float* __restrict__ F_input,
                        const float* __restrict__ selfconv,
                        const float* __restrict__ W_pos, const float* __restrict__ alpha,
                        const float* __restrict__ conv_w,
                        const float* __restrict__ ln_w, const float* __restrict__ ln_b,
                        const float* __restrict__ lnl_w, const float* __restrict__ lnl_b,
                        const int* __restrict__ coords,
                        const float* __restrict__ sums, const float* __restrict__ counts,
                        const u32* __restrict__ nbrcnt, const u32* __restrict__ nbrlst,
                        float* __restrict__ out, int n, int nwaves){
    const int lane = threadIdx.x & 63;
    const int wave = (blockIdx.x * blockDim.x + threadIdx.x) >> 6;

    const float wx = W_pos[lane*3+0], wy = W_pos[lane*3+1], wz = W_pos[lane*3+2];
    const float al = alpha[lane];
    const float lnwv = ln_w[lane], lnbv = ln_b[lane];
    const float llwv = lnl_w[lane], llbv = lnl_b[lane];

    int i = wave;
    if(i >= n) return;

    // stage A (current point)
    int siA = __builtin_amdgcn_readfirstlane(i);
    int4 cA = ((const int4*)coords)[siA];
    int segA = ((cA.x >> 3) << 10) | ((cA.y >> 3) << 5) | (cA.z >> 3);
    const float* spA = sums + (size_t)segA * 192;
    float s0A = spA[lane], s1A = spA[64+lane], s2A = spA[128+lane];
    float cntA = counts[segA];
    float FA = F_input[(size_t)siA*64 + lane];
    float ScA = selfconv[(size_t)siA*64 + lane];
    u32 ncA = nbrcnt[siA];
    u32 e0A = nbrlst[(size_t)siA*8];

    for(; i < n; ){
        const int inext = i + nwaves;
        const bool hB = inext < n;
        // prefetch stage B (next point) — issues before A's compute
        int siB = 0; int4 cB = cA; float s0B=0,s1B=0,s2B=0,cntB=0,FB=0,ScB=0;
        u32 ncB = 0, e0B = 0;
        if(hB){
            siB = __builtin_amdgcn_readfirstlane(inext);
            cB = ((const int4*)coords)[siB];
            int segB = ((cB.x >> 3) << 10) | ((cB.y >> 3) << 5) | (cB.z >> 3);
            const float* spB = sums + (size_t)segB * 192;
            s0B = spB[lane]; s1B = spB[64+lane]; s2B = spB[128+lane];
            cntB = counts[segB];
            FB = F_input[(size_t)siB*64 + lane];
            ScB = selfconv[(size_t)siB*64 + lane];
            ncB = nbrcnt[siB];
            e0B = nbrlst[(size_t)siB*8];
        }

        // ---- compute A ----
        float pos = ((float)cA.x*wx + (float)cA.y*wy + (float)cA.z*wz) * al;
        float sn = __sinf(pos), cs = __cosf(pos);
        float inv = 1.f / fmaxf(cntA, 1.f);
        float newF = fmaf(s0A*inv, cs, fmaf(s1A*inv, sn, s2A*inv - FA*pos));
        float local = ScA;

        u32 cc = ncA > 8u ? 8u : ncA;
        if(cc){
            u32 e = e0A;
            u32 c2 = 0;
            for(;;){
                u32 k = e >> 25, pi = e & 0x1FFFFFFu;
                const float4* gv = (const float4*)(feats + (size_t)pi * 64);
                const float* cw = conv_w + (size_t)k * 4096;
#pragma unroll
                for(int q = 0; q < 16; ++q){
                    float4 g = gv[q];
                    local = fmaf(g.x, cw[(4*q    )*64 + lane], local);
                    local = fmaf(g.y, cw[(4*q + 1)*64 + lane], local);
                    local = fmaf(g.z, cw[(4*q + 2)*64 + lane], local);
                    local = fmaf(g.w, cw[(4*q + 3)*64 + lane], local);
                }
                if(++c2 >= cc) break;
                e = nbrlst[(size_t)siA*8 + c2];
            }
        }

        float m1 = wave_sum(newF) * (1.f/64.f);
        float t1 = newF - m1;
        float v1 = wave_sum(t1*t1) * (1.f/64.f);
        float a1 = t1 * rsqrtf(v1 + EPSV) * lnwv + lnbv;

        float m2 = wave_sum(local) * (1.f/64.f);
        float t2 = local - m2;
        float v2 = wave_sum(t2*t2) * (1.f/64.f);
        float a2 = t2 * rsqrtf(v2 + EPSV) * llwv + llbv;

        out[(size_t)siA*64 + lane] = fmaxf(a1 + a2, 0.f);

        // ---- rotate B -> A ----
        i = inext;
        if(hB){
            siA = siB; cA = cB;
            s0A = s0B; s1A = s1B; s2A = s2B; cntA = cntB;
            FA = FB; ScA = ScB; ncA = ncB; e0A = e0B;
        }
    }
}

extern "C" void kernel_launch(void* const* d_in, const int* in_sizes, int n_in,
                              void* d_out, int out_size, void* d_ws, size_t ws_size,
                              hipStream_t stream) {
    (void)n_in; (void)out_size; (void)ws_size;
    const float* feats    = (const float*)d_in[0];
    const float* W_pre    = (const float*)d_in[1];
    const float* ln_pre_w = (const float*)d_in[2];
    const float* ln_pre_b = (const float*)d_in[3];
    const float* W_pos    = (const float*)d_in[4];
    const float* alpha    = (const float*)d_in[5];
    const float* conv_w   = (const float*)d_in[6];
    const float* ln_w     = (const float*)d_in[7];
    const float* ln_b     = (const float*)d_in[8];
    const float* lnl_w    = (const float*)d_in[9];
    const float* lnl_b    = (const float*)d_in[10];
    const int*   coords   = (const int*)d_in[11];

    const int n = in_sizes[0] / 64;

    char* ws = (char*)d_ws;
    size_t o = 0;
    u64*   hash    = (u64*)(ws + o);   o += (size_t)HSIZE * 8;          // 8,388,608
    size_t zoff    = o;
    u32*   bm      = (u32*)(ws + o);   o += 2097152;                    // 2MB bitmap
    float* sums    = (float*)(ws + o); o += 25165824;                   // 32768*192*4
    float* counts  = (float*)(ws + o); o += 131072;                     // 32768*4
    u32*   nbrcnt  = (u32*)(ws + o);   o += ((size_t)n*4 + 255) & ~(size_t)255;
    size_t zspan   = o - zoff;
    u32*   nbrlst  = (u32*)(ws + o);   o += (size_t)n * 32;             // 8 slots/pt
    float* F_input = (float*)(ws + o); o += (size_t)n * 256;
    float* selfconv= (float*)(ws + o); o += (size_t)n * 256;
    // total o = 145,382,912 bytes <= 145,702,912 proven available (r2/r4)

    hipMemsetAsync(hash, 0xFF, (size_t)HSIZE * 8, stream);
    hipMemsetAsync(ws + zoff, 0, zspan, stream);

    k_scatter<<<(n + 255)/256, 256, 0, stream>>>(coords, hash, bm, n);
    k_nbr<<<(n*27 + 255)/256, 256, 0, stream>>>(coords, hash, bm, nbrcnt, nbrlst, n);
    k_pre<<<2048, 256, 0, stream>>>(feats, W_pre, ln_pre_w, ln_pre_b, conv_w,
                                    W_pos, alpha, coords, F_input, selfconv,
                                    sums, counts, n, 8192);
    k_final<<<2048, 256, 0, stream>>>(feats, F_input, selfconv, W_pos, alpha, conv_w,
                                      ln_w, ln_b, lnl_w, lnl_b, coords,
                                      sums, counts, nbrcnt, nbrlst,
                                      (float*)d_out, n, 8192);
}